// Round 17
// baseline (126.405 us; speedup 1.0000x reference)
//
#include <hip/hip_runtime.h>
#include <stdint.h>

#define SEQ 4096
#define DM 768
#define NH 12
#define HD 64

typedef __attribute__((ext_vector_type(8))) short bf8;
typedef __attribute__((ext_vector_type(4))) float f4;
typedef __attribute__((ext_vector_type(16))) float f32x16;

static __device__ __forceinline__ f4 mfma_bf16(bf8 a, bf8 b, f4 c) {
  return __builtin_amdgcn_mfma_f32_16x16x32_bf16(a, b, c, 0, 0, 0);
}
static __device__ __forceinline__ f32x16 mfma32(bf8 a, bf8 b, f32x16 c) {
  return __builtin_amdgcn_mfma_f32_32x32x16_bf16(a, b, c, 0, 0, 0);
}

// RNE float->bf16 (bit pattern)
static __device__ __forceinline__ unsigned short f2bf(float f) {
  unsigned int u = __float_as_uint(f);
  u += 0x7FFFu + ((u >> 16) & 1u);
  return (unsigned short)(u >> 16);
}

// packed f32 pair -> bf16 pair (lo in low 16, hi in high 16)
static __device__ __forceinline__ unsigned int cvtpk(float lo, float hi) {
  unsigned int r;
  asm("v_cvt_pk_bf16_f32 %0, %1, %2" : "=v"(r) : "v"(lo), "v"(hi));
  return r;
}

static __device__ __forceinline__ void gload_lds16(const void* g, void* l) {
  __builtin_amdgcn_global_load_lds(
      (const __attribute__((address_space(1))) void*)g,
      (__attribute__((address_space(3))) void*)l, 16, 0, 0);
}

// ---- cast x (fp32) -> bf16 -----------------------------------------------
__global__ __launch_bounds__(256) void k_cvt(const float* __restrict__ x,
                                             unsigned short* __restrict__ xb) {
  int i = (blockIdx.x * 256 + threadIdx.x) * 4;
  float4 v = *reinterpret_cast<const float4*>(x + i);
  ushort4 o;
  o.x = f2bf(v.x); o.y = f2bf(v.y); o.z = f2bf(v.z); o.w = f2bf(v.w);
  *reinterpret_cast<ushort4*>(xb + i) = o;
}

// ---- transpose+cast weights: WT[z][n][k] = bf16(W[k][n]) -----------------
__global__ __launch_bounds__(256) void k_tw(const float* __restrict__ w0,
                                            const float* __restrict__ w1,
                                            const float* __restrict__ w2,
                                            const float* __restrict__ w3,
                                            unsigned short* __restrict__ wt) {
  const float* W = blockIdx.z == 0 ? w0 : blockIdx.z == 1 ? w1
                 : blockIdx.z == 2 ? w2 : w3;
  unsigned short* WT = wt + (size_t)blockIdx.z * DM * DM;
  __shared__ float t[32][33];
  int c0 = blockIdx.x * 32, r0 = blockIdx.y * 32;
  int lx = threadIdx.x & 31, ly = threadIdx.x >> 5;
#pragma unroll
  for (int rr = 0; rr < 32; rr += 8)
    t[ly + rr][lx] = W[(size_t)(r0 + ly + rr) * DM + c0 + lx];
  __syncthreads();
#pragma unroll
  for (int rr = 0; rr < 32; rr += 8)
    WT[(size_t)(c0 + ly + rr) * DM + r0 + lx] = f2bf(t[lx][ly + rr]);
}

// ---- bf16 MFMA GEMM, 128x128 tile, 4 waves (2x2), wave tile 64x64 --------
// DOUBLE-BUFFERED staging (R17): two sA/sB pairs; stage(k+1) issues after
// the barrier that drains buf(k), so its latency is covered by compute(k).
// Staging/swizzle/fragment math byte-identical to the proven BK=32 form.
// MODE 3: fused QKV. Bt = [2304][768] (Wq^T|Wk^T|Wv^T). Routes by
//         zone=col/768: Q->per-head*qscale, K->per-head,
//         V->tiled [h][ktile32][d][ks32] (contiguous 4KB per 32-k tile).
// MODE 2: out-proj, fp32 [row][768] + bias[col].
template <int MODE>
__global__ __launch_bounds__(256) void k_gemm2(const unsigned short* __restrict__ A,
                                               const unsigned short* __restrict__ Bt,
                                               unsigned short* __restrict__ Qh,
                                               unsigned short* __restrict__ Kh,
                                               unsigned short* __restrict__ Vtl,
                                               float* __restrict__ Cf,
                                               const float* __restrict__ bias,
                                               float qscale) {
  __shared__ unsigned short sA[2][128 * 32];
  __shared__ unsigned short sB[2][128 * 32];
  const int t = threadIdx.x, lane = t & 63, w = t >> 6;
  const int wr = w >> 1, wc = w & 1;
  const int c = lane & 15, g = lane >> 4;
  const int brow = blockIdx.x * 128, bcol = blockIdx.y * 128;
  f4 acc[4][4] = {};

#define G2_STAGE(buf, k0) do {                                                \
    _Pragma("unroll")                                                         \
    for (int i_ = 0; i_ < 2; ++i_) {                                          \
      int slot_ = w * 2 + i_;                                                 \
      int chunk_ = slot_ * 64 + lane;                                         \
      int row_ = chunk_ >> 2;                                                 \
      int sl_ = (chunk_ & 3) ^ ((row_ >> 1) & 3);                             \
      gload_lds16(A + (size_t)(brow + row_) * DM + (k0) + sl_ * 8,            \
                  &sA[buf][slot_ * 512]);                                     \
    }                                                                         \
    _Pragma("unroll")                                                         \
    for (int i_ = 0; i_ < 2; ++i_) {                                          \
      int slot_ = w * 2 + i_;                                                 \
      int chunk_ = slot_ * 64 + lane;                                         \
      int row_ = chunk_ >> 2;                                                 \
      int sl_ = (chunk_ & 3) ^ ((row_ >> 1) & 3);                             \
      gload_lds16(Bt + (size_t)(bcol + row_) * DM + (k0) + sl_ * 8,           \
                  &sB[buf][slot_ * 512]);                                     \
    }                                                                         \
  } while (0)

#define G2_COMPUTE(buf) do {                                                  \
    bf8 af_[4], bf_[4];                                                       \
    _Pragma("unroll")                                                         \
    for (int m_ = 0; m_ < 4; ++m_) {                                          \
      int row_ = wr * 64 + m_ * 16 + c;                                       \
      int off_ = row_ * 64 + ((g * 16) ^ (((row_ >> 1) & 3) << 4));           \
      af_[m_] = *reinterpret_cast<const bf8*>(                                \
          reinterpret_cast<const char*>(sA[buf]) + off_);                     \
    }                                                                         \
    _Pragma("unroll")                                                         \
    for (int n_ = 0; n_ < 4; ++n_) {                                          \
      int row_ = wc * 64 + n_ * 16 + c;                                       \
      int off_ = row_ * 64 + ((g * 16) ^ (((row_ >> 1) & 3) << 4));           \
      bf_[n_] = *reinterpret_cast<const bf8*>(                                \
          reinterpret_cast<const char*>(sB[buf]) + off_);                     \
    }                                                                         \
    _Pragma("unroll")                                                         \
    for (int m_ = 0; m_ < 4; ++m_)                                            \
      _Pragma("unroll")                                                       \
      for (int n_ = 0; n_ < 4; ++n_)                                          \
        acc[m_][n_] = mfma_bf16(af_[m_], bf_[n_], acc[m_][n_]);               \
  } while (0)

  G2_STAGE(0, 0);
  for (int k0 = 0; k0 < DM; k0 += 64) {
    __syncthreads();                 // drains buf0(k0); prior buf1 reads done
    if (k0 + 32 < DM) G2_STAGE(1, k0 + 32);
    G2_COMPUTE(0);
    __syncthreads();                 // drains buf1; buf0 reads done
    if (k0 + 64 < DM) G2_STAGE(0, k0 + 64);
    G2_COMPUTE(1);
  }
#undef G2_STAGE
#undef G2_COMPUTE

#pragma unroll
  for (int m = 0; m < 4; ++m) {
#pragma unroll
    for (int n = 0; n < 4; ++n) {
      int col = bcol + wc * 64 + n * 16 + c;
      int row0 = brow + wr * 64 + m * 16 + g * 4;
      if (MODE == 3) {
        int zone = col / 768;
        int ci = col - zone * 768;
        int h = ci >> 6, d = ci & 63;
        if (zone == 0) {
#pragma unroll
          for (int r = 0; r < 4; ++r)
            Qh[((size_t)h * SEQ + row0 + r) * 64 + d] = f2bf(acc[m][n][r] * qscale);
        } else if (zone == 1) {
#pragma unroll
          for (int r = 0; r < 4; ++r)
            Kh[((size_t)h * SEQ + row0 + r) * 64 + d] = f2bf(acc[m][n][r]);
        } else {
          ushort4 p;
          p.x = f2bf(acc[m][n][0]); p.y = f2bf(acc[m][n][1]);
          p.z = f2bf(acc[m][n][2]); p.w = f2bf(acc[m][n][3]);
          // row0 = k index; tile = row0>>5, ks = row0&31 (row0%4==0 -> in-tile)
          *reinterpret_cast<ushort4*>(
              Vtl + ((((size_t)h * 128 + (row0 >> 5)) * 64 + d) * 32 + (row0 & 31))) = p;
        }
      } else {
#pragma unroll
        for (int r = 0; r < 4; ++r)
          Cf[(size_t)(row0 + r) * DM + col] = acc[m][n][r] + bias[col];
      }
    }
  }
}

// ---- attention helpers ----------------------------------------------------
#define PSWAP(a, b) asm volatile("v_permlane32_swap_b32 %0, %1" : "+v"(a), "+v"(b))
#define SGB() __builtin_amdgcn_sched_barrier(0)

// Stage a 32x64 bf16 K tile (contiguous 4KB, 128-B rows) into LDS.
// Source pre-swizzled (chunk ^= row&7) to match the swizzled ds_read.
#define STAGE4K(srcbase, tile, dst) do {                                      \
    const unsigned short* s_ = (srcbase) + (size_t)(tile) * 2048 + kLaneOffK; \
    _Pragma("unroll")                                                         \
    for (int j_ = 0; j_ < 4; ++j_)                                            \
      gload_lds16(s_ + j_ * 512, (dst) + j_ * 1024);                          \
  } while (0)

// Stage a 64x32 bf16 V tile (contiguous 4KB, 64-B rows). Source pre-swizzled:
// chunk ^= (row&3)^((row>>2)&3)^((row>>4)&3); row = 16j + (lane>>2), so the
// (row>>4)&3 term is the batch index j (16j>>4 = j).
#define STAGE4KV(srcbase, tile, dst) do {                                     \
    const unsigned short* s_ = (srcbase) + (size_t)(tile) * 2048;             \
    _Pragma("unroll")                                                         \
    for (int j_ = 0; j_ < 4; ++j_) {                                          \
      int c_ = (lane & 3) ^ ((lane >> 2) & 3) ^ ((lane >> 4) & 3) ^ j_;       \
      gload_lds16(s_ + j_ * 512 + (lane >> 2) * 32 + c_ * 8,                  \
                  (dst) + j_ * 1024);                                         \
    }                                                                         \
  } while (0)

// 16 P-values (one f32x16, already masked) -> exp -> two bf8 B-fragments.
#define PBUILD(sv, pfx, pfy) do {                                             \
    float p0_ = __builtin_amdgcn_exp2f(sv[0] - mn_);                          \
    float p1_ = __builtin_amdgcn_exp2f(sv[1] - mn_);                          \
    float p2_ = __builtin_amdgcn_exp2f(sv[2] - mn_);                          \
    float p3_ = __builtin_amdgcn_exp2f(sv[3] - mn_);                          \
    float p4_ = __builtin_amdgcn_exp2f(sv[4] - mn_);                          \
    float p5_ = __builtin_amdgcn_exp2f(sv[5] - mn_);                          \
    float p6_ = __builtin_amdgcn_exp2f(sv[6] - mn_);                          \
    float p7_ = __builtin_amdgcn_exp2f(sv[7] - mn_);                          \
    unsigned int wa0_ = cvtpk(p0_, p1_), wa1_ = cvtpk(p2_, p3_);              \
    unsigned int wb0_ = cvtpk(p4_, p5_), wb1_ = cvtpk(p6_, p7_);              \
    ls_ += ((p0_ + p1_) + (p2_ + p3_)) + ((p4_ + p5_) + (p6_ + p7_));         \
    float q0_ = __builtin_amdgcn_exp2f(sv[8] - mn_);                          \
    float q1_ = __builtin_amdgcn_exp2f(sv[9] - mn_);                          \
    float q2_ = __builtin_amdgcn_exp2f(sv[10] - mn_);                         \
    float q3_ = __builtin_amdgcn_exp2f(sv[11] - mn_);                         \
    float q4_ = __builtin_amdgcn_exp2f(sv[12] - mn_);                         \
    float q5_ = __builtin_amdgcn_exp2f(sv[13] - mn_);                         \
    float q6_ = __builtin_amdgcn_exp2f(sv[14] - mn_);                         \
    float q7_ = __builtin_amdgcn_exp2f(sv[15] - mn_);                         \
    unsigned int wc0_ = cvtpk(q0_, q1_), wc1_ = cvtpk(q2_, q3_);              \
    unsigned int wd0_ = cvtpk(q4_, q5_), wd1_ = cvtpk(q6_, q7_);              \
    ls_ += ((q0_ + q1_) + (q2_ + q3_)) + ((q4_ + q5_) + (q6_ + q7_));         \
    PSWAP(wa0_, wb0_);                                                        \
    PSWAP(wa1_, wb1_);                                                        \
    PSWAP(wc0_, wd0_);                                                        \
    PSWAP(wc1_, wd1_);                                                        \
    uint4 u0_ = {wa0_, wa1_, wb0_, wb1_};                                     \
    uint4 u1_ = {wc0_, wc1_, wd0_, wd1_};                                     \
    pfx = *reinterpret_cast<bf8*>(&u0_);                                      \
    pfy = *reinterpret_cast<bf8*>(&u1_);                                      \
  } while (0)

#define FMAX8(v, i0) fmaxf(fmaxf(fmaxf(v[i0], v[i0+1]), fmaxf(v[i0+2], v[i0+3])), \
                           fmaxf(fmaxf(v[i0+4], v[i0+5]), fmaxf(v[i0+6], v[i0+7])))

// Cross-half (lane i <-> i+32) reduce via permlane32_swap. The opaque asm
// copy forces 'cp' into a register DISTINCT from 'x' (R7 lesson).
#define XHALF_MAX(x) do {                                                     \
    float cp_ = (x);                                                          \
    asm volatile("" : "+v"(cp_));                                             \
    PSWAP((x), cp_);                                                          \
    (x) = fmaxf((x), cp_);                                                    \
  } while (0)
#define XHALF_ADD(x) do {                                                     \
    float cp_ = (x);                                                          \
    asm volatile("" : "+v"(cp_));                                             \
    PSWAP((x), cp_);                                                          \
    (x) = (x) + cp_;                                                          \
  } while (0)

// One KVBLK=32 step. Fence discipline identical to R13/R14 (proven):
// each buffer's ds_reads are SGB/lgkmcnt(0)/SGB-fenced before restage and
// before the consuming MFMAs. Defer-max (T13, THR=8, log2 domain).
#define STEP32(t, stage_) do {                                                \
    asm volatile("s_waitcnt vmcnt(0)" ::: "memory");                          \
    SGB();                                                                    \
    const char* kr0_ = kbuf + ql * 128;                                       \
    bf8 ka0_ = *(const bf8*)(kr0_ + (((hi) ^ xq) << 4));                      \
    bf8 ka1_ = *(const bf8*)(kr0_ + (((2 + hi) ^ xq) << 4));                  \
    bf8 ka2_ = *(const bf8*)(kr0_ + (((4 + hi) ^ xq) << 4));                  \
    bf8 ka3_ = *(const bf8*)(kr0_ + (((6 + hi) ^ xq) << 4));                  \
    SGB();                                                                    \
    asm volatile("s_waitcnt lgkmcnt(0)" ::: "memory");                        \
    SGB();                                                                    \
    if (stage_) STAGE4K(Khp, (t) + 4, kbuf);                                  \
    f32x16 s0_ = {};                                                          \
    __builtin_amdgcn_s_setprio(1);                                            \
    s0_ = mfma32(ka0_, qf[0], s0_);                                           \
    s0_ = mfma32(ka1_, qf[1], s0_);                                           \
    s0_ = mfma32(ka2_, qf[2], s0_);                                           \
    s0_ = mfma32(ka3_, qf[3], s0_);                                           \
    __builtin_amdgcn_s_setprio(0);                                            \
    if ((t) == dt) {                                                          \
      _Pragma("unroll")                                                       \
      for (int r_ = 0; r_ < 16; ++r_) {                                       \
        int kr_ = (t) * 32 + (r_ & 3) + 8 * (r_ >> 2) + 4 * hi;               \
        s0_[r_] = (kr_ > qg) ? -1e30f : s0_[r_];                              \
      }                                                                       \
    }                                                                         \
    float tm_ = fmaxf(FMAX8(s0_, 0), FMAX8(s0_, 8));                          \
    XHALF_MAX(tm_);                                                           \
    float mn_, al_;                                                           \
    if (__all(tm_ <= m + 8.f)) {                                              \
      mn_ = m;                                                                \
      al_ = 1.0f;                                                             \
    } else {                                                                  \
      mn_ = fmaxf(m, tm_);                                                    \
      al_ = __builtin_amdgcn_exp2f(m - mn_);                                  \
      m = mn_;                                                                \
      _Pragma("unroll")                                                       \
      for (int r_ = 0; r_ < 16; ++r_) { o0[r_] *= al_; o1[r_] *= al_; }       \
    }                                                                         \
    float ls_ = 0.f;                                                          \
    bf8 pfA0_, pfA1_;                                                         \
    PBUILD(s0_, pfA0_, pfA1_);                                                \
    XHALF_ADD(ls_);                                                           \
    l = l * al_ + ls_;                                                        \
    bf8 va0_ = *(const bf8*)(vbuf + ql * 64 + (((hi) ^ prA) << 4));           \
    bf8 va1_ = *(const bf8*)(vbuf + ql * 64 + (((2 + hi) ^ prA) << 4));       \
    bf8 vb0_ = *(const bf8*)(vbuf + (32 + ql) * 64 + (((hi) ^ prB) << 4));    \
    bf8 vb1_ = *(const bf8*)(vbuf + (32 + ql) * 64 + (((2 + hi) ^ prB) << 4));\
    SGB();                                                                    \
    asm volatile("s_waitcnt lgkmcnt(0)" ::: "memory");                        \
    SGB();                                                                    \
    if (stage_) STAGE4KV(Vtp, (t) + 4, vbuf);                                 \
    __builtin_amdgcn_s_setprio(1);                                            \
    o0 = mfma32(va0_, pfA0_, o0);                                             \
    o0 = mfma32(va1_, pfA1_, o0);                                             \
    o1 = mfma32(vb0_, pfA0_, o1);                                             \
    o1 = mfma32(vb1_, pfA1_, o1);                                             \
    __builtin_amdgcn_s_setprio(0);                                            \
  } while (0)

// ---- causal flash attention: paired q-tiles + split-K x4 + XCD chunking --
// KVBLK=32 -> 8KB staging/wave -> 33.8KB LDS -> 4 blocks/CU (16 waves).
// K and V LDS-staged from contiguous 4KB tiles, one step ahead, no
// over-staging. sO merge overlays the staging region (pre-merge barrier).
__global__ __launch_bounds__(256, 4) void k_attn(const unsigned short* __restrict__ Qh,
                                                 const unsigned short* __restrict__ Kh,
                                                 const unsigned short* __restrict__ Vt,
                                                 unsigned short* __restrict__ ctx) {
  const int tid = threadIdx.x;
  const int lane = tid & 63;
  const int w = tid >> 6;  // split-K wave index, 0..3
  const int ql = lane & 31, hi = lane >> 5;
  const int xq = ql & 7;
  const int prA = (ql & 3) ^ ((ql >> 2) & 3) ^ ((ql >> 4) & 3);
  const int prB = prA ^ 2;

  const int L = (int)blockIdx.x;          // 0..767
  const int W = (L & 7) * 96 + (L >> 3);  // XCD-chunked work id
  const int h = W >> 6;
  const int b = W & 63;

  __shared__ __align__(16) char smem[33792];
  char* kbuf = smem + w * 4096;           // [0,16K)
  char* vbuf = smem + 16384 + w * 4096;   // [16K,32K)
  float* sO = (float*)smem;               // [4][64][32] overlays staging
  float* sM = (float*)(smem + 32768);     // [4][32]
  float* sL = (float*)(smem + 33280);     // [4][32]

  const unsigned short* Khp = Kh + (size_t)h * SEQ * 64;
  const unsigned short* Qhp = Qh + (size_t)h * SEQ * 64;
  const unsigned short* Vtp = Vt + (size_t)h * SEQ * 64;  // tiled [128][64][32]
  // K staging source offset (shorts): row = lane>>3, chunk^row (128-B rows)
  const int kLaneOffK = (lane >> 3) * 64 + ((lane & 7) ^ (lane >> 3)) * 8;

  for (int ph = 0; ph < 2; ++ph) {
    const int qt = ph ? (127 - b) : b;
    const int qg = qt * 32 + ql;
    const int dt = qt;  // diagonal 32-tile
    bf8 qf[4];
    {
      const unsigned short* qp = Qhp + (size_t)qg * 64 + hi * 8;
      qf[0] = *reinterpret_cast<const bf8*>(qp);
      qf[1] = *reinterpret_cast<const bf8*>(qp + 16);
      qf[2] = *reinterpret_cast<const bf8*>(qp + 32);
      qf[3] = *reinterpret_cast<const bf8*>(qp + 48);
    }
    f32x16 o0 = {}, o1 = {};
    float m = -1e30f, l = 0.f;

    const int nt = (dt >= w) ? ((dt - w) >> 2) + 1 : 0;
    if (nt > 0) {
      STAGE4K(Khp, w, kbuf);
      STAGE4KV(Vtp, w, vbuf);
      for (int i = 0; i < nt; ++i) {
        const int t = w + 4 * i;
        STEP32(t, (i + 1 < nt));
      }
    }
    __syncthreads();  // all staging consumed; buffers reusable as sO

    // ---- 4-way split-K merge via LDS (sO overlays staging region) ----
#pragma unroll
    for (int r = 0; r < 16; ++r) {
      int dr = (r & 3) + 8 * (r >> 2) + 4 * hi;
      sO[w * 2048 + dr * 32 + ql] = o0[r];
      sO[w * 2048 + (32 + dr) * 32 + ql] = o1[r];
    }
    if (hi == 0) { sM[w * 32 + ql] = m; sL[w * 32 + ql] = l; }
    __syncthreads();
    {
      const int q = tid & 31;
      const int dblk = tid >> 5;  // 0..7, 8 d-values each
      float m0 = sM[q], m1 = sM[32 + q], m2 = sM[64 + q], m3 = sM[96 + q];
      float mn = fmaxf(fmaxf(m0, m1), fmaxf(m2, m3));
      float a0 = __builtin_amdgcn_exp2f(m0 - mn);
      float a1 = __builtin_amdgcn_exp2f(m1 - mn);
      float a2 = __builtin_amdgcn_exp2f(m2 - mn);
      float a3 = __builtin_amdgcn_exp2f(m3 - mn);
      float inv = 1.f / (a0 * sL[q] + a1 * sL[32 + q] + a2 * sL[64 + q] + a3 * sL[96 + q]);
      a0 *= inv; a1 *= inv; a2 *= inv; a3 *= inv;
      unsigned short* cp = ctx + (size_t)(qt * 32 + q) * DM + h * HD + dblk * 8;
#pragma unroll
      for (int j = 0; j < 8; j += 2) {
        int d = dblk * 8 + j;
        float v0 = sO[d * 32 + q] * a0 + sO[2048 + d * 32 + q] * a1 +
                   sO[4096 + d * 32 + q] * a2 + sO[6144 + d * 32 + q] * a3;
        float v1 = sO[(d + 1) * 32 + q] * a0 + sO[2048 + (d + 1) * 32 + q] * a1 +
                   sO[4096 + (d + 1) * 32 + q] * a2 + sO[6144 + (d + 1) * 32 + q] * a3;
        *reinterpret_cast<unsigned int*>(cp + j) = cvtpk(v0, v1);
      }
    }
    __syncthreads();  // merge reads done before phase-2 restage
  }
}

extern "C" void kernel_launch(void* const* d_in, const int* in_sizes, int n_in,
                              void* d_out, int out_size, void* d_ws, size_t ws_size,
                              hipStream_t stream) {
  const float* x  = (const float*)d_in[0];
  const float* Wq = (const float*)d_in[1];
  const float* Wk = (const float*)d_in[2];
  const float* Wv = (const float*)d_in[3];
  const float* Wo = (const float*)d_in[4];
  const float* bo = (const float*)d_in[5];

  unsigned short* xb = (unsigned short*)d_ws;
  unsigned short* wt = xb + (size_t)SEQ * DM;
  unsigned short* Qh = wt + (size_t)4 * DM * DM;
  unsigned short* Kh = Qh + (size_t)SEQ * DM;
  unsigned short* Vt = Kh + (size_t)SEQ * DM;
  unsigned short* cx = Vt + (size_t)SEQ * DM;

  const float qscale = 1.4426950408889634f / 8.0f;  // log2(e)/sqrt(HD)

  k_cvt<<<(SEQ * DM) / 1024, 256, 0, stream>>>(x, xb);
  k_tw<<<dim3(24, 24, 4), 256, 0, stream>>>(Wq, Wk, Wv, Wo, wt);
  // fused QKV GEMM over Bt=[2304][768] (wt holds Wq^T|Wk^T|Wv^T contiguous)
  k_gemm2<3><<<dim3(SEQ / 128, 2304 / 128), 256, 0, stream>>>(
      xb, wt, Qh, Kh, Vt, nullptr, nullptr, qscale);
  k_attn<<<dim3(768), 256, 0, stream>>>(Qh, Kh, Vt, cx);
  k_gemm2<2><<<dim3(SEQ / 128, DM / 128), 256, 0, stream>>>(
      cx, wt + (size_t)3 * DM * DM, nullptr, nullptr, nullptr,
      (float*)d_out, bo, 1.0f);
}

// Round 18
// 121.555 us; speedup vs baseline: 1.0399x; 1.0399x over previous
//
#include <hip/hip_runtime.h>
#include <stdint.h>

#define SEQ 4096
#define DM 768
#define NH 12
#define HD 64

typedef __attribute__((ext_vector_type(8))) short bf8;
typedef __attribute__((ext_vector_type(4))) float f4;
typedef __attribute__((ext_vector_type(16))) float f32x16;

static __device__ __forceinline__ f4 mfma_bf16(bf8 a, bf8 b, f4 c) {
  return __builtin_amdgcn_mfma_f32_16x16x32_bf16(a, b, c, 0, 0, 0);
}
static __device__ __forceinline__ f32x16 mfma32(bf8 a, bf8 b, f32x16 c) {
  return __builtin_amdgcn_mfma_f32_32x32x16_bf16(a, b, c, 0, 0, 0);
}

// RNE float->bf16 (bit pattern)
static __device__ __forceinline__ unsigned short f2bf(float f) {
  unsigned int u = __float_as_uint(f);
  u += 0x7FFFu + ((u >> 16) & 1u);
  return (unsigned short)(u >> 16);
}

// packed f32 pair -> bf16 pair (lo in low 16, hi in high 16)
static __device__ __forceinline__ unsigned int cvtpk(float lo, float hi) {
  unsigned int r;
  asm("v_cvt_pk_bf16_f32 %0, %1, %2" : "=v"(r) : "v"(lo), "v"(hi));
  return r;
}

static __device__ __forceinline__ void gload_lds16(const void* g, void* l) {
  __builtin_amdgcn_global_load_lds(
      (const __attribute__((address_space(1))) void*)g,
      (__attribute__((address_space(3))) void*)l, 16, 0, 0);
}

// ---- cast x (fp32) -> bf16 -----------------------------------------------
__global__ __launch_bounds__(256) void k_cvt(const float* __restrict__ x,
                                             unsigned short* __restrict__ xb) {
  int i = (blockIdx.x * 256 + threadIdx.x) * 4;
  float4 v = *reinterpret_cast<const float4*>(x + i);
  ushort4 o;
  o.x = f2bf(v.x); o.y = f2bf(v.y); o.z = f2bf(v.z); o.w = f2bf(v.w);
  *reinterpret_cast<ushort4*>(xb + i) = o;
}

// ---- transpose+cast weights: WT[z][n][k] = bf16(W[k][n]) -----------------
__global__ __launch_bounds__(256) void k_tw(const float* __restrict__ w0,
                                            const float* __restrict__ w1,
                                            const float* __restrict__ w2,
                                            const float* __restrict__ w3,
                                            unsigned short* __restrict__ wt) {
  const float* W = blockIdx.z == 0 ? w0 : blockIdx.z == 1 ? w1
                 : blockIdx.z == 2 ? w2 : w3;
  unsigned short* WT = wt + (size_t)blockIdx.z * DM * DM;
  __shared__ float t[32][33];
  int c0 = blockIdx.x * 32, r0 = blockIdx.y * 32;
  int lx = threadIdx.x & 31, ly = threadIdx.x >> 5;
#pragma unroll
  for (int rr = 0; rr < 32; rr += 8)
    t[ly + rr][lx] = W[(size_t)(r0 + ly + rr) * DM + c0 + lx];
  __syncthreads();
#pragma unroll
  for (int rr = 0; rr < 32; rr += 8)
    WT[(size_t)(c0 + ly + rr) * DM + r0 + lx] = f2bf(t[lx][ly + rr]);
}

// ---- bf16 MFMA GEMM, 128x128 tile, 4 waves (2x2), wave tile 64x64 --------
// Single-buffered (R16-proven; R17 dbuf regressed). 1D grid with
// XCD-chunked swizzle (T1): W=(L&7)*(NWG/8)+(L>>3), bx-major chunks
// (by=W%NY) so B (3.5MB QKV / 1.1MB out-proj) stays L2-resident per XCD
// and each A-panel is reused NY times from L2. NWG%8==0 -> bijective.
// MODE 3: fused QKV. Bt = [2304][768] (Wq^T|Wk^T|Wv^T). Routes by
//         zone=col/768: Q->per-head*qscale, K->per-head,
//         V->tiled [h][ktile32][d][ks32] (contiguous 4KB per 32-k tile).
// MODE 2: out-proj, fp32 [row][768] + bias[col].
template <int MODE, int NY>
__global__ __launch_bounds__(256) void k_gemm2(const unsigned short* __restrict__ A,
                                               const unsigned short* __restrict__ Bt,
                                               unsigned short* __restrict__ Qh,
                                               unsigned short* __restrict__ Kh,
                                               unsigned short* __restrict__ Vtl,
                                               float* __restrict__ Cf,
                                               const float* __restrict__ bias,
                                               float qscale) {
  __shared__ unsigned short sA[128 * 32];
  __shared__ unsigned short sB[128 * 32];
  const int t = threadIdx.x, lane = t & 63, w = t >> 6;
  const int wr = w >> 1, wc = w & 1;
  const int c = lane & 15, g = lane >> 4;
  constexpr int NWG = 32 * NY;
  const int L = (int)blockIdx.x;
  const int W = (L & 7) * (NWG / 8) + (L >> 3);
  const int brow = (W / NY) * 128, bcol = (W % NY) * 128;
  f4 acc[4][4] = {};
  for (int k0 = 0; k0 < DM; k0 += 32) {
#pragma unroll
    for (int i = 0; i < 2; ++i) {
      int slot = w * 2 + i;
      int chunk = slot * 64 + lane;
      int row = chunk >> 2;
      int sl = (chunk & 3) ^ ((row >> 1) & 3);
      gload_lds16(A + (size_t)(brow + row) * DM + k0 + sl * 8, &sA[slot * 512]);
    }
#pragma unroll
    for (int i = 0; i < 2; ++i) {
      int slot = w * 2 + i;
      int chunk = slot * 64 + lane;
      int row = chunk >> 2;
      int sl = (chunk & 3) ^ ((row >> 1) & 3);
      gload_lds16(Bt + (size_t)(bcol + row) * DM + k0 + sl * 8, &sB[slot * 512]);
    }
    __syncthreads();
    bf8 af[4], bfr[4];
#pragma unroll
    for (int m = 0; m < 4; ++m) {
      int row = wr * 64 + m * 16 + c;
      int off = row * 64 + ((g * 16) ^ (((row >> 1) & 3) << 4));
      af[m] = *reinterpret_cast<const bf8*>(reinterpret_cast<const char*>(sA) + off);
    }
#pragma unroll
    for (int n = 0; n < 4; ++n) {
      int row = wc * 64 + n * 16 + c;
      int off = row * 64 + ((g * 16) ^ (((row >> 1) & 3) << 4));
      bfr[n] = *reinterpret_cast<const bf8*>(reinterpret_cast<const char*>(sB) + off);
    }
#pragma unroll
    for (int m = 0; m < 4; ++m)
#pragma unroll
      for (int n = 0; n < 4; ++n)
        acc[m][n] = mfma_bf16(af[m], bfr[n], acc[m][n]);
    __syncthreads();
  }
#pragma unroll
  for (int m = 0; m < 4; ++m) {
#pragma unroll
    for (int n = 0; n < 4; ++n) {
      int col = bcol + wc * 64 + n * 16 + c;
      int row0 = brow + wr * 64 + m * 16 + g * 4;
      if (MODE == 3) {
        int zone = col / 768;
        int ci = col - zone * 768;
        int h = ci >> 6, d = ci & 63;
        if (zone == 0) {
#pragma unroll
          for (int r = 0; r < 4; ++r)
            Qh[((size_t)h * SEQ + row0 + r) * 64 + d] = f2bf(acc[m][n][r] * qscale);
        } else if (zone == 1) {
#pragma unroll
          for (int r = 0; r < 4; ++r)
            Kh[((size_t)h * SEQ + row0 + r) * 64 + d] = f2bf(acc[m][n][r]);
        } else {
          ushort4 p;
          p.x = f2bf(acc[m][n][0]); p.y = f2bf(acc[m][n][1]);
          p.z = f2bf(acc[m][n][2]); p.w = f2bf(acc[m][n][3]);
          // row0 = k index; tile = row0>>5, ks = row0&31 (row0%4==0 -> in-tile)
          *reinterpret_cast<ushort4*>(
              Vtl + ((((size_t)h * 128 + (row0 >> 5)) * 64 + d) * 32 + (row0 & 31))) = p;
        }
      } else {
#pragma unroll
        for (int r = 0; r < 4; ++r)
          Cf[(size_t)(row0 + r) * DM + col] = acc[m][n][r] + bias[col];
      }
    }
  }
}

// ---- attention helpers ----------------------------------------------------
#define PSWAP(a, b) asm volatile("v_permlane32_swap_b32 %0, %1" : "+v"(a), "+v"(b))
#define SGB() __builtin_amdgcn_sched_barrier(0)

// Stage a 32x64 bf16 K tile (contiguous 4KB, 128-B rows) into LDS.
// Source pre-swizzled (chunk ^= row&7) to match the swizzled ds_read.
#define STAGE4K(srcbase, tile, dst) do {                                      \
    const unsigned short* s_ = (srcbase) + (size_t)(tile) * 2048 + kLaneOffK; \
    _Pragma("unroll")                                                         \
    for (int j_ = 0; j_ < 4; ++j_)                                            \
      gload_lds16(s_ + j_ * 512, (dst) + j_ * 1024);                          \
  } while (0)

// Stage a 64x32 bf16 V tile (contiguous 4KB, 64-B rows). Source pre-swizzled:
// chunk ^= (row&3)^((row>>2)&3)^((row>>4)&3); row = 16j + (lane>>2), so the
// (row>>4)&3 term is the batch index j (16j>>4 = j).
#define STAGE4KV(srcbase, tile, dst) do {                                     \
    const unsigned short* s_ = (srcbase) + (size_t)(tile) * 2048;             \
    _Pragma("unroll")                                                         \
    for (int j_ = 0; j_ < 4; ++j_) {                                          \
      int c_ = (lane & 3) ^ ((lane >> 2) & 3) ^ ((lane >> 4) & 3) ^ j_;       \
      gload_lds16(s_ + j_ * 512 + (lane >> 2) * 32 + c_ * 8,                  \
                  (dst) + j_ * 1024);                                         \
    }                                                                         \
  } while (0)

// 16 P-values (one f32x16, already masked) -> exp -> two bf8 B-fragments.
#define PBUILD(sv, pfx, pfy) do {                                             \
    float p0_ = __builtin_amdgcn_exp2f(sv[0] - mn_);                          \
    float p1_ = __builtin_amdgcn_exp2f(sv[1] - mn_);                          \
    float p2_ = __builtin_amdgcn_exp2f(sv[2] - mn_);                          \
    float p3_ = __builtin_amdgcn_exp2f(sv[3] - mn_);                          \
    float p4_ = __builtin_amdgcn_exp2f(sv[4] - mn_);                          \
    float p5_ = __builtin_amdgcn_exp2f(sv[5] - mn_);                          \
    float p6_ = __builtin_amdgcn_exp2f(sv[6] - mn_);                          \
    float p7_ = __builtin_amdgcn_exp2f(sv[7] - mn_);                          \
    unsigned int wa0_ = cvtpk(p0_, p1_), wa1_ = cvtpk(p2_, p3_);              \
    unsigned int wb0_ = cvtpk(p4_, p5_), wb1_ = cvtpk(p6_, p7_);              \
    ls_ += ((p0_ + p1_) + (p2_ + p3_)) + ((p4_ + p5_) + (p6_ + p7_));         \
    float q0_ = __builtin_amdgcn_exp2f(sv[8] - mn_);                          \
    float q1_ = __builtin_amdgcn_exp2f(sv[9] - mn_);                          \
    float q2_ = __builtin_amdgcn_exp2f(sv[10] - mn_);                         \
    float q3_ = __builtin_amdgcn_exp2f(sv[11] - mn_);                         \
    float q4_ = __builtin_amdgcn_exp2f(sv[12] - mn_);                         \
    float q5_ = __builtin_amdgcn_exp2f(sv[13] - mn_);                         \
    float q6_ = __builtin_amdgcn_exp2f(sv[14] - mn_);                         \
    float q7_ = __builtin_amdgcn_exp2f(sv[15] - mn_);                         \
    unsigned int wc0_ = cvtpk(q0_, q1_), wc1_ = cvtpk(q2_, q3_);              \
    unsigned int wd0_ = cvtpk(q4_, q5_), wd1_ = cvtpk(q6_, q7_);              \
    ls_ += ((q0_ + q1_) + (q2_ + q3_)) + ((q4_ + q5_) + (q6_ + q7_));         \
    PSWAP(wa0_, wb0_);                                                        \
    PSWAP(wa1_, wb1_);                                                        \
    PSWAP(wc0_, wd0_);                                                        \
    PSWAP(wc1_, wd1_);                                                        \
    uint4 u0_ = {wa0_, wa1_, wb0_, wb1_};                                     \
    uint4 u1_ = {wc0_, wc1_, wd0_, wd1_};                                     \
    pfx = *reinterpret_cast<bf8*>(&u0_);                                      \
    pfy = *reinterpret_cast<bf8*>(&u1_);                                      \
  } while (0)

#define FMAX8(v, i0) fmaxf(fmaxf(fmaxf(v[i0], v[i0+1]), fmaxf(v[i0+2], v[i0+3])), \
                           fmaxf(fmaxf(v[i0+4], v[i0+5]), fmaxf(v[i0+6], v[i0+7])))

// Cross-half (lane i <-> i+32) reduce via permlane32_swap. The opaque asm
// copy forces 'cp' into a register DISTINCT from 'x' (R7 lesson).
#define XHALF_MAX(x) do {                                                     \
    float cp_ = (x);                                                          \
    asm volatile("" : "+v"(cp_));                                             \
    PSWAP((x), cp_);                                                          \
    (x) = fmaxf((x), cp_);                                                    \
  } while (0)
#define XHALF_ADD(x) do {                                                     \
    float cp_ = (x);                                                          \
    asm volatile("" : "+v"(cp_));                                             \
    PSWAP((x), cp_);                                                          \
    (x) = (x) + cp_;                                                          \
  } while (0)

// One KVBLK=32 step. Fence discipline identical to R13-R16 (proven):
// each buffer's ds_reads are SGB/lgkmcnt(0)/SGB-fenced before restage and
// before the consuming MFMAs. Defer-max (T13, THR=8, log2 domain).
#define STEP32(t, stage_) do {                                                \
    asm volatile("s_waitcnt vmcnt(0)" ::: "memory");                          \
    SGB();                                                                    \
    const char* kr0_ = kbuf + ql * 128;                                       \
    bf8 ka0_ = *(const bf8*)(kr0_ + (((hi) ^ xq) << 4));                      \
    bf8 ka1_ = *(const bf8*)(kr0_ + (((2 + hi) ^ xq) << 4));                  \
    bf8 ka2_ = *(const bf8*)(kr0_ + (((4 + hi) ^ xq) << 4));                  \
    bf8 ka3_ = *(const bf8*)(kr0_ + (((6 + hi) ^ xq) << 4));                  \
    SGB();                                                                    \
    asm volatile("s_waitcnt lgkmcnt(0)" ::: "memory");                        \
    SGB();                                                                    \
    if (stage_) STAGE4K(Khp, (t) + 4, kbuf);                                  \
    f32x16 s0_ = {};                                                          \
    __builtin_amdgcn_s_setprio(1);                                            \
    s0_ = mfma32(ka0_, qf[0], s0_);                                           \
    s0_ = mfma32(ka1_, qf[1], s0_);                                           \
    s0_ = mfma32(ka2_, qf[2], s0_);                                           \
    s0_ = mfma32(ka3_, qf[3], s0_);                                           \
    __builtin_amdgcn_s_setprio(0);                                            \
    if ((t) == dt) {                                                          \
      _Pragma("unroll")                                                       \
      for (int r_ = 0; r_ < 16; ++r_) {                                       \
        int kr_ = (t) * 32 + (r_ & 3) + 8 * (r_ >> 2) + 4 * hi;               \
        s0_[r_] = (kr_ > qg) ? -1e30f : s0_[r_];                              \
      }                                                                       \
    }                                                                         \
    float tm_ = fmaxf(FMAX8(s0_, 0), FMAX8(s0_, 8));                          \
    XHALF_MAX(tm_);                                                           \
    float mn_, al_;                                                           \
    if (__all(tm_ <= m + 8.f)) {                                              \
      mn_ = m;                                                                \
      al_ = 1.0f;                                                             \
    } else {                                                                  \
      mn_ = fmaxf(m, tm_);                                                    \
      al_ = __builtin_amdgcn_exp2f(m - mn_);                                  \
      m = mn_;                                                                \
      _Pragma("unroll")                                                       \
      for (int r_ = 0; r_ < 16; ++r_) { o0[r_] *= al_; o1[r_] *= al_; }       \
    }                                                                         \
    float ls_ = 0.f;                                                          \
    bf8 pfA0_, pfA1_;                                                         \
    PBUILD(s0_, pfA0_, pfA1_);                                                \
    XHALF_ADD(ls_);                                                           \
    l = l * al_ + ls_;                                                        \
    bf8 va0_ = *(const bf8*)(vbuf + ql * 64 + (((hi) ^ prA) << 4));           \
    bf8 va1_ = *(const bf8*)(vbuf + ql * 64 + (((2 + hi) ^ prA) << 4));       \
    bf8 vb0_ = *(const bf8*)(vbuf + (32 + ql) * 64 + (((hi) ^ prB) << 4));    \
    bf8 vb1_ = *(const bf8*)(vbuf + (32 + ql) * 64 + (((2 + hi) ^ prB) << 4));\
    SGB();                                                                    \
    asm volatile("s_waitcnt lgkmcnt(0)" ::: "memory");                        \
    SGB();                                                                    \
    if (stage_) STAGE4KV(Vtp, (t) + 4, vbuf);                                 \
    __builtin_amdgcn_s_setprio(1);                                            \
    o0 = mfma32(va0_, pfA0_, o0);                                             \
    o0 = mfma32(va1_, pfA1_, o0);                                             \
    o1 = mfma32(vb0_, pfA0_, o1);                                             \
    o1 = mfma32(vb1_, pfA1_, o1);                                             \
    __builtin_amdgcn_s_setprio(0);                                            \
  } while (0)

// ---- causal flash attention: paired q-tiles + split-K x4 + XCD chunking --
// KVBLK=32 -> 8KB staging/wave -> 33.8KB LDS -> 4 blocks/CU (16 waves).
// K and V LDS-staged from contiguous 4KB tiles, one step ahead, no
// over-staging. sO merge overlays the staging region (pre-merge barrier).
__global__ __launch_bounds__(256, 4) void k_attn(const unsigned short* __restrict__ Qh,
                                                 const unsigned short* __restrict__ Kh,
                                                 const unsigned short* __restrict__ Vt,
                                                 unsigned short* __restrict__ ctx) {
  const int tid = threadIdx.x;
  const int lane = tid & 63;
  const int w = tid >> 6;  // split-K wave index, 0..3
  const int ql = lane & 31, hi = lane >> 5;
  const int xq = ql & 7;
  const int prA = (ql & 3) ^ ((ql >> 2) & 3) ^ ((ql >> 4) & 3);
  const int prB = prA ^ 2;

  const int L = (int)blockIdx.x;          // 0..767
  const int W = (L & 7) * 96 + (L >> 3);  // XCD-chunked work id
  const int h = W >> 6;
  const int b = W & 63;

  __shared__ __align__(16) char smem[33792];
  char* kbuf = smem + w * 4096;           // [0,16K)
  char* vbuf = smem + 16384 + w * 4096;   // [16K,32K)
  float* sO = (float*)smem;               // [4][64][32] overlays staging
  float* sM = (float*)(smem + 32768);     // [4][32]
  float* sL = (float*)(smem + 33280);     // [4][32]

  const unsigned short* Khp = Kh + (size_t)h * SEQ * 64;
  const unsigned short* Qhp = Qh + (size_t)h * SEQ * 64;
  const unsigned short* Vtp = Vt + (size_t)h * SEQ * 64;  // tiled [128][64][32]
  // K staging source offset (shorts): row = lane>>3, chunk^row (128-B rows)
  const int kLaneOffK = (lane >> 3) * 64 + ((lane & 7) ^ (lane >> 3)) * 8;

  for (int ph = 0; ph < 2; ++ph) {
    const int qt = ph ? (127 - b) : b;
    const int qg = qt * 32 + ql;
    const int dt = qt;  // diagonal 32-tile
    bf8 qf[4];
    {
      const unsigned short* qp = Qhp + (size_t)qg * 64 + hi * 8;
      qf[0] = *reinterpret_cast<const bf8*>(qp);
      qf[1] = *reinterpret_cast<const bf8*>(qp + 16);
      qf[2] = *reinterpret_cast<const bf8*>(qp + 32);
      qf[3] = *reinterpret_cast<const bf8*>(qp + 48);
    }
    f32x16 o0 = {}, o1 = {};
    float m = -1e30f, l = 0.f;

    const int nt = (dt >= w) ? ((dt - w) >> 2) + 1 : 0;
    if (nt > 0) {
      STAGE4K(Khp, w, kbuf);
      STAGE4KV(Vtp, w, vbuf);
      for (int i = 0; i < nt; ++i) {
        const int t = w + 4 * i;
        STEP32(t, (i + 1 < nt));
      }
    }
    __syncthreads();  // all staging consumed; buffers reusable as sO

    // ---- 4-way split-K merge via LDS (sO overlays staging region) ----
#pragma unroll
    for (int r = 0; r < 16; ++r) {
      int dr = (r & 3) + 8 * (r >> 2) + 4 * hi;
      sO[w * 2048 + dr * 32 + ql] = o0[r];
      sO[w * 2048 + (32 + dr) * 32 + ql] = o1[r];
    }
    if (hi == 0) { sM[w * 32 + ql] = m; sL[w * 32 + ql] = l; }
    __syncthreads();
    {
      const int q = tid & 31;
      const int dblk = tid >> 5;  // 0..7, 8 d-values each
      float m0 = sM[q], m1 = sM[32 + q], m2 = sM[64 + q], m3 = sM[96 + q];
      float mn = fmaxf(fmaxf(m0, m1), fmaxf(m2, m3));
      float a0 = __builtin_amdgcn_exp2f(m0 - mn);
      float a1 = __builtin_amdgcn_exp2f(m1 - mn);
      float a2 = __builtin_amdgcn_exp2f(m2 - mn);
      float a3 = __builtin_amdgcn_exp2f(m3 - mn);
      float inv = 1.f / (a0 * sL[q] + a1 * sL[32 + q] + a2 * sL[64 + q] + a3 * sL[96 + q]);
      a0 *= inv; a1 *= inv; a2 *= inv; a3 *= inv;
      unsigned short* cp = ctx + (size_t)(qt * 32 + q) * DM + h * HD + dblk * 8;
#pragma unroll
      for (int j = 0; j < 8; j += 2) {
        int d = dblk * 8 + j;
        float v0 = sO[d * 32 + q] * a0 + sO[2048 + d * 32 + q] * a1 +
                   sO[4096 + d * 32 + q] * a2 + sO[6144 + d * 32 + q] * a3;
        float v1 = sO[(d + 1) * 32 + q] * a0 + sO[2048 + (d + 1) * 32 + q] * a1 +
                   sO[4096 + (d + 1) * 32 + q] * a2 + sO[6144 + (d + 1) * 32 + q] * a3;
        *reinterpret_cast<unsigned int*>(cp + j) = cvtpk(v0, v1);
      }
    }
    __syncthreads();  // merge reads done before phase-2 restage
  }
}

extern "C" void kernel_launch(void* const* d_in, const int* in_sizes, int n_in,
                              void* d_out, int out_size, void* d_ws, size_t ws_size,
                              hipStream_t stream) {
  const float* x  = (const float*)d_in[0];
  const float* Wq = (const float*)d_in[1];
  const float* Wk = (const float*)d_in[2];
  const float* Wv = (const float*)d_in[3];
  const float* Wo = (const float*)d_in[4];
  const float* bo = (const float*)d_in[5];

  unsigned short* xb = (unsigned short*)d_ws;
  unsigned short* wt = xb + (size_t)SEQ * DM;
  unsigned short* Qh = wt + (size_t)4 * DM * DM;
  unsigned short* Kh = Qh + (size_t)SEQ * DM;
  unsigned short* Vt = Kh + (size_t)SEQ * DM;
  unsigned short* cx = Vt + (size_t)SEQ * DM;

  const float qscale = 1.4426950408889634f / 8.0f;  // log2(e)/sqrt(HD)

  k_cvt<<<(SEQ * DM) / 1024, 256, 0, stream>>>(x, xb);
  k_tw<<<dim3(24, 24, 4), 256, 0, stream>>>(Wq, Wk, Wv, Wo, wt);
  // fused QKV GEMM over Bt=[2304][768] (wt holds Wq^T|Wk^T|Wv^T contiguous)
  k_gemm2<3, 18><<<dim3(SEQ / 128 * 18), 256, 0, stream>>>(
      xb, wt, Qh, Kh, Vt, nullptr, nullptr, qscale);
  k_attn<<<dim3(768), 256, 0, stream>>>(Qh, Kh, Vt, cx);
  k_gemm2<2, 6><<<dim3(SEQ / 128 * 6), 256, 0, stream>>>(
      cx, wt + (size_t)3 * DM * DM, nullptr, nullptr, nullptr,
      (float*)d_out, bo, 1.0f);
}

// Round 19
// 118.027 us; speedup vs baseline: 1.0710x; 1.0299x over previous
//
#include <hip/hip_runtime.h>
#include <stdint.h>

#define SEQ 4096
#define DM 768
#define NH 12
#define HD 64

typedef __attribute__((ext_vector_type(8))) short bf8;
typedef __attribute__((ext_vector_type(4))) float f4;
typedef __attribute__((ext_vector_type(16))) float f32x16;

static __device__ __forceinline__ f4 mfma_bf16(bf8 a, bf8 b, f4 c) {
  return __builtin_amdgcn_mfma_f32_16x16x32_bf16(a, b, c, 0, 0, 0);
}
static __device__ __forceinline__ f32x16 mfma32(bf8 a, bf8 b, f32x16 c) {
  return __builtin_amdgcn_mfma_f32_32x32x16_bf16(a, b, c, 0, 0, 0);
}

// RNE float->bf16 (bit pattern)
static __device__ __forceinline__ unsigned short f2bf(float f) {
  unsigned int u = __float_as_uint(f);
  u += 0x7FFFu + ((u >> 16) & 1u);
  return (unsigned short)(u >> 16);
}

// packed f32 pair -> bf16 pair (lo in low 16, hi in high 16)
static __device__ __forceinline__ unsigned int cvtpk(float lo, float hi) {
  unsigned int r;
  asm("v_cvt_pk_bf16_f32 %0, %1, %2" : "=v"(r) : "v"(lo), "v"(hi));
  return r;
}

static __device__ __forceinline__ void gload_lds16(const void* g, void* l) {
  __builtin_amdgcn_global_load_lds(
      (const __attribute__((address_space(1))) void*)g,
      (__attribute__((address_space(3))) void*)l, 16, 0, 0);
}

// ---- fused prologue: transpose-cast W (blocks 0..2303) + cast x (rest) ----
// tw part: WT[z][n][k] = bf16(W[k][n]), z in 0..3, 24x24 32x32-tiles.
// cvt part: xb = bf16(x), 1024 elems/block.
__global__ __launch_bounds__(256) void k_pro(const float* __restrict__ x,
                                             const float* __restrict__ w0,
                                             const float* __restrict__ w1,
                                             const float* __restrict__ w2,
                                             const float* __restrict__ w3,
                                             unsigned short* __restrict__ xb,
                                             unsigned short* __restrict__ wt) {
  const int id = (int)blockIdx.x;
  if (id < 2304) {
    const int z = id / 576, rem = id % 576;
    const int by = rem / 24, bx = rem % 24;
    const float* W = z == 0 ? w0 : z == 1 ? w1 : z == 2 ? w2 : w3;
    unsigned short* WT = wt + (size_t)z * DM * DM;
    __shared__ float t[32][33];
    int c0 = bx * 32, r0 = by * 32;
    int lx = threadIdx.x & 31, ly = threadIdx.x >> 5;
#pragma unroll
    for (int rr = 0; rr < 32; rr += 8)
      t[ly + rr][lx] = W[(size_t)(r0 + ly + rr) * DM + c0 + lx];
    __syncthreads();
#pragma unroll
    for (int rr = 0; rr < 32; rr += 8)
      WT[(size_t)(c0 + ly + rr) * DM + r0 + lx] = f2bf(t[lx][ly + rr]);
  } else {
    int i = ((id - 2304) * 256 + threadIdx.x) * 4;
    float4 v = *reinterpret_cast<const float4*>(x + i);
    ushort4 o;
    o.x = f2bf(v.x); o.y = f2bf(v.y); o.z = f2bf(v.z); o.w = f2bf(v.w);
    *reinterpret_cast<ushort4*>(xb + i) = o;
  }
}

// ---- bf16 MFMA GEMM, 128x128 tile, 4 waves (2x2), wave tile 64x64 --------
// Single-buffered (R16-proven). 1D grid with XCD-chunked swizzle (T1):
// W=(L&7)*(NWG/8)+(L>>3), bx-major chunks (by=W%NY) so B stays
// L2-resident per XCD. NWG%8==0 -> bijective.
// MODE 3: fused QKV. Bt = [2304][768] (Wq^T|Wk^T|Wv^T). Routes by
//         zone=col/768: Q->per-head*qscale, K->per-head,
//         V->tiled [h][ktile32][d][ks32] (contiguous 4KB per 32-k tile).
// MODE 2: out-proj, fp32 [row][768] + bias[col].
template <int MODE, int NY>
__global__ __launch_bounds__(256) void k_gemm2(const unsigned short* __restrict__ A,
                                               const unsigned short* __restrict__ Bt,
                                               unsigned short* __restrict__ Qh,
                                               unsigned short* __restrict__ Kh,
                                               unsigned short* __restrict__ Vtl,
                                               float* __restrict__ Cf,
                                               const float* __restrict__ bias,
                                               float qscale) {
  __shared__ unsigned short sA[128 * 32];
  __shared__ unsigned short sB[128 * 32];
  const int t = threadIdx.x, lane = t & 63, w = t >> 6;
  const int wr = w >> 1, wc = w & 1;
  const int c = lane & 15, g = lane >> 4;
  constexpr int NWG = 32 * NY;
  const int L = (int)blockIdx.x;
  const int W = (L & 7) * (NWG / 8) + (L >> 3);
  const int brow = (W / NY) * 128, bcol = (W % NY) * 128;
  f4 acc[4][4] = {};
  for (int k0 = 0; k0 < DM; k0 += 32) {
#pragma unroll
    for (int i = 0; i < 2; ++i) {
      int slot = w * 2 + i;
      int chunk = slot * 64 + lane;
      int row = chunk >> 2;
      int sl = (chunk & 3) ^ ((row >> 1) & 3);
      gload_lds16(A + (size_t)(brow + row) * DM + k0 + sl * 8, &sA[slot * 512]);
    }
#pragma unroll
    for (int i = 0; i < 2; ++i) {
      int slot = w * 2 + i;
      int chunk = slot * 64 + lane;
      int row = chunk >> 2;
      int sl = (chunk & 3) ^ ((row >> 1) & 3);
      gload_lds16(Bt + (size_t)(bcol + row) * DM + k0 + sl * 8, &sB[slot * 512]);
    }
    __syncthreads();
    bf8 af[4], bfr[4];
#pragma unroll
    for (int m = 0; m < 4; ++m) {
      int row = wr * 64 + m * 16 + c;
      int off = row * 64 + ((g * 16) ^ (((row >> 1) & 3) << 4));
      af[m] = *reinterpret_cast<const bf8*>(reinterpret_cast<const char*>(sA) + off);
    }
#pragma unroll
    for (int n = 0; n < 4; ++n) {
      int row = wc * 64 + n * 16 + c;
      int off = row * 64 + ((g * 16) ^ (((row >> 1) & 3) << 4));
      bfr[n] = *reinterpret_cast<const bf8*>(reinterpret_cast<const char*>(sB) + off);
    }
#pragma unroll
    for (int m = 0; m < 4; ++m)
#pragma unroll
      for (int n = 0; n < 4; ++n)
        acc[m][n] = mfma_bf16(af[m], bfr[n], acc[m][n]);
    __syncthreads();
  }
#pragma unroll
  for (int m = 0; m < 4; ++m) {
#pragma unroll
    for (int n = 0; n < 4; ++n) {
      int col = bcol + wc * 64 + n * 16 + c;
      int row0 = brow + wr * 64 + m * 16 + g * 4;
      if (MODE == 3) {
        int zone = col / 768;
        int ci = col - zone * 768;
        int h = ci >> 6, d = ci & 63;
        if (zone == 0) {
#pragma unroll
          for (int r = 0; r < 4; ++r)
            Qh[((size_t)h * SEQ + row0 + r) * 64 + d] = f2bf(acc[m][n][r] * qscale);
        } else if (zone == 1) {
#pragma unroll
          for (int r = 0; r < 4; ++r)
            Kh[((size_t)h * SEQ + row0 + r) * 64 + d] = f2bf(acc[m][n][r]);
        } else {
          ushort4 p;
          p.x = f2bf(acc[m][n][0]); p.y = f2bf(acc[m][n][1]);
          p.z = f2bf(acc[m][n][2]); p.w = f2bf(acc[m][n][3]);
          // row0 = k index; tile = row0>>5, ks = row0&31 (row0%4==0 -> in-tile)
          *reinterpret_cast<ushort4*>(
              Vtl + ((((size_t)h * 128 + (row0 >> 5)) * 64 + d) * 32 + (row0 & 31))) = p;
        }
      } else {
#pragma unroll
        for (int r = 0; r < 4; ++r)
          Cf[(size_t)(row0 + r) * DM + col] = acc[m][n][r] + bias[col];
      }
    }
  }
}

// ---- attention helpers ----------------------------------------------------
#define PSWAP(a, b) asm volatile("v_permlane32_swap_b32 %0, %1" : "+v"(a), "+v"(b))
#define SGB() __builtin_amdgcn_sched_barrier(0)

// Stage a 32x64 bf16 K tile (contiguous 4KB, 128-B rows) into LDS.
// Source pre-swizzled (chunk ^= row&7) to match the swizzled ds_read.
#define STAGE4K(srcbase, tile, dst) do {                                      \
    const unsigned short* s_ = (srcbase) + (size_t)(tile) * 2048 + kLaneOffK; \
    _Pragma("unroll")                                                         \
    for (int j_ = 0; j_ < 4; ++j_)                                            \
      gload_lds16(s_ + j_ * 512, (dst) + j_ * 1024);                          \
  } while (0)

// Stage a 64x32 bf16 V tile (contiguous 4KB, 64-B rows). Source pre-swizzled:
// chunk ^= (row&3)^((row>>2)&3)^((row>>4)&3); row = 16j + (lane>>2), so the
// (row>>4)&3 term is the batch index j (16j>>4 = j).
#define STAGE4KV(srcbase, tile, dst) do {                                     \
    const unsigned short* s_ = (srcbase) + (size_t)(tile) * 2048;             \
    _Pragma("unroll")                                                         \
    for (int j_ = 0; j_ < 4; ++j_) {                                          \
      int c_ = (lane & 3) ^ ((lane >> 2) & 3) ^ ((lane >> 4) & 3) ^ j_;       \
      gload_lds16(s_ + j_ * 512 + (lane >> 2) * 32 + c_ * 8,                  \
                  (dst) + j_ * 1024);                                         \
    }                                                                         \
  } while (0)

// 16 P-values (one f32x16, already masked) -> exp -> two bf8 B-fragments.
#define PBUILD(sv, pfx, pfy) do {                                             \
    float p0_ = __builtin_amdgcn_exp2f(sv[0] - mn_);                          \
    float p1_ = __builtin_amdgcn_exp2f(sv[1] - mn_);                          \
    float p2_ = __builtin_amdgcn_exp2f(sv[2] - mn_);                          \
    float p3_ = __builtin_amdgcn_exp2f(sv[3] - mn_);                          \
    float p4_ = __builtin_amdgcn_exp2f(sv[4] - mn_);                          \
    float p5_ = __builtin_amdgcn_exp2f(sv[5] - mn_);                          \
    float p6_ = __builtin_amdgcn_exp2f(sv[6] - mn_);                          \
    float p7_ = __builtin_amdgcn_exp2f(sv[7] - mn_);                          \
    unsigned int wa0_ = cvtpk(p0_, p1_), wa1_ = cvtpk(p2_, p3_);              \
    unsigned int wb0_ = cvtpk(p4_, p5_), wb1_ = cvtpk(p6_, p7_);              \
    ls_ += ((p0_ + p1_) + (p2_ + p3_)) + ((p4_ + p5_) + (p6_ + p7_));         \
    float q0_ = __builtin_amdgcn_exp2f(sv[8] - mn_);                          \
    float q1_ = __builtin_amdgcn_exp2f(sv[9] - mn_);                          \
    float q2_ = __builtin_amdgcn_exp2f(sv[10] - mn_);                         \
    float q3_ = __builtin_amdgcn_exp2f(sv[11] - mn_);                         \
    float q4_ = __builtin_amdgcn_exp2f(sv[12] - mn_);                         \
    float q5_ = __builtin_amdgcn_exp2f(sv[13] - mn_);                         \
    float q6_ = __builtin_amdgcn_exp2f(sv[14] - mn_);                         \
    float q7_ = __builtin_amdgcn_exp2f(sv[15] - mn_);                         \
    unsigned int wc0_ = cvtpk(q0_, q1_), wc1_ = cvtpk(q2_, q3_);              \
    unsigned int wd0_ = cvtpk(q4_, q5_), wd1_ = cvtpk(q6_, q7_);              \
    ls_ += ((q0_ + q1_) + (q2_ + q3_)) + ((q4_ + q5_) + (q6_ + q7_));         \
    PSWAP(wa0_, wb0_);                                                        \
    PSWAP(wa1_, wb1_);                                                        \
    PSWAP(wc0_, wd0_);                                                        \
    PSWAP(wc1_, wd1_);                                                        \
    uint4 u0_ = {wa0_, wa1_, wb0_, wb1_};                                     \
    uint4 u1_ = {wc0_, wc1_, wd0_, wd1_};                                     \
    pfx = *reinterpret_cast<bf8*>(&u0_);                                      \
    pfy = *reinterpret_cast<bf8*>(&u1_);                                      \
  } while (0)

#define FMAX8(v, i0) fmaxf(fmaxf(fmaxf(v[i0], v[i0+1]), fmaxf(v[i0+2], v[i0+3])), \
                           fmaxf(fmaxf(v[i0+4], v[i0+5]), fmaxf(v[i0+6], v[i0+7])))

// Cross-half (lane i <-> i+32) reduce via permlane32_swap. The opaque asm
// copy forces 'cp' into a register DISTINCT from 'x' (R7 lesson).
#define XHALF_MAX(x) do {                                                     \
    float cp_ = (x);                                                          \
    asm volatile("" : "+v"(cp_));                                             \
    PSWAP((x), cp_);                                                          \
    (x) = fmaxf((x), cp_);                                                    \
  } while (0)
#define XHALF_ADD(x) do {                                                     \
    float cp_ = (x);                                                          \
    asm volatile("" : "+v"(cp_));                                             \
    PSWAP((x), cp_);                                                          \
    (x) = (x) + cp_;                                                          \
  } while (0)

// One KVBLK=32 step. Fence discipline identical to R13-R18 (proven):
// each buffer's ds_reads are SGB/lgkmcnt(0)/SGB-fenced before restage and
// before the consuming MFMAs. Defer-max (T13, THR=8, log2 domain).
#define STEP32(t, stage_) do {                                                \
    asm volatile("s_waitcnt vmcnt(0)" ::: "memory");                          \
    SGB();                                                                    \
    const char* kr0_ = kbuf + ql * 128;                                       \
    bf8 ka0_ = *(const bf8*)(kr0_ + (((hi) ^ xq) << 4));                      \
    bf8 ka1_ = *(const bf8*)(kr0_ + (((2 + hi) ^ xq) << 4));                  \
    bf8 ka2_ = *(const bf8*)(kr0_ + (((4 + hi) ^ xq) << 4));                  \
    bf8 ka3_ = *(const bf8*)(kr0_ + (((6 + hi) ^ xq) << 4));                  \
    SGB();                                                                    \
    asm volatile("s_waitcnt lgkmcnt(0)" ::: "memory");                        \
    SGB();                                                                    \
    if (stage_) STAGE4K(Khp, (t) + 4, kbuf);                                  \
    f32x16 s0_ = {};                                                          \
    __builtin_amdgcn_s_setprio(1);                                            \
    s0_ = mfma32(ka0_, qf[0], s0_);                                           \
    s0_ = mfma32(ka1_, qf[1], s0_);                                           \
    s0_ = mfma32(ka2_, qf[2], s0_);                                           \
    s0_ = mfma32(ka3_, qf[3], s0_);                                           \
    __builtin_amdgcn_s_setprio(0);                                            \
    if ((t) == dt) {                                                          \
      _Pragma("unroll")                                                       \
      for (int r_ = 0; r_ < 16; ++r_) {                                       \
        int kr_ = (t) * 32 + (r_ & 3) + 8 * (r_ >> 2) + 4 * hi;               \
        s0_[r_] = (kr_ > qg) ? -1e30f : s0_[r_];                              \
      }                                                                       \
    }                                                                         \
    float tm_ = fmaxf(FMAX8(s0_, 0), FMAX8(s0_, 8));                          \
    XHALF_MAX(tm_);                                                           \
    float mn_, al_;                                                           \
    if (__all(tm_ <= m + 8.f)) {                                              \
      mn_ = m;                                                                \
      al_ = 1.0f;                                                             \
    } else {                                                                  \
      mn_ = fmaxf(m, tm_);                                                    \
      al_ = __builtin_amdgcn_exp2f(m - mn_);                                  \
      m = mn_;                                                                \
      _Pragma("unroll")                                                       \
      for (int r_ = 0; r_ < 16; ++r_) { o0[r_] *= al_; o1[r_] *= al_; }       \
    }                                                                         \
    float ls_ = 0.f;                                                          \
    bf8 pfA0_, pfA1_;                                                         \
    PBUILD(s0_, pfA0_, pfA1_);                                                \
    XHALF_ADD(ls_);                                                           \
    l = l * al_ + ls_;                                                        \
    bf8 va0_ = *(const bf8*)(vbuf + ql * 64 + (((hi) ^ prA) << 4));           \
    bf8 va1_ = *(const bf8*)(vbuf + ql * 64 + (((2 + hi) ^ prA) << 4));       \
    bf8 vb0_ = *(const bf8*)(vbuf + (32 + ql) * 64 + (((hi) ^ prB) << 4));    \
    bf8 vb1_ = *(const bf8*)(vbuf + (32 + ql) * 64 + (((2 + hi) ^ prB) << 4));\
    SGB();                                                                    \
    asm volatile("s_waitcnt lgkmcnt(0)" ::: "memory");                        \
    SGB();                                                                    \
    if (stage_) STAGE4KV(Vtp, (t) + 4, vbuf);                                 \
    __builtin_amdgcn_s_setprio(1);                                            \
    o0 = mfma32(va0_, pfA0_, o0);                                             \
    o0 = mfma32(va1_, pfA1_, o0);                                             \
    o1 = mfma32(vb0_, pfA0_, o1);                                             \
    o1 = mfma32(vb1_, pfA1_, o1);                                             \
    __builtin_amdgcn_s_setprio(0);                                            \
  } while (0)

// ---- causal flash attention: paired q-tiles + split-K x4 + XCD chunking --
// KVBLK=32 -> 8KB staging/wave -> 33.8KB LDS -> 4 blocks/CU (16 waves).
// K and V LDS-staged from contiguous 4KB tiles, one step ahead, no
// over-staging. sO merge overlays the staging region (pre-merge barrier).
__global__ __launch_bounds__(256, 4) void k_attn(const unsigned short* __restrict__ Qh,
                                                 const unsigned short* __restrict__ Kh,
                                                 const unsigned short* __restrict__ Vt,
                                                 unsigned short* __restrict__ ctx) {
  const int tid = threadIdx.x;
  const int lane = tid & 63;
  const int w = tid >> 6;  // split-K wave index, 0..3
  const int ql = lane & 31, hi = lane >> 5;
  const int xq = ql & 7;
  const int prA = (ql & 3) ^ ((ql >> 2) & 3) ^ ((ql >> 4) & 3);
  const int prB = prA ^ 2;

  const int L = (int)blockIdx.x;          // 0..767
  const int W = (L & 7) * 96 + (L >> 3);  // XCD-chunked work id
  const int h = W >> 6;
  const int b = W & 63;

  __shared__ __align__(16) char smem[33792];
  char* kbuf = smem + w * 4096;           // [0,16K)
  char* vbuf = smem + 16384 + w * 4096;   // [16K,32K)
  float* sO = (float*)smem;               // [4][64][32] overlays staging
  float* sM = (float*)(smem + 32768);     // [4][32]
  float* sL = (float*)(smem + 33280);     // [4][32]

  const unsigned short* Khp = Kh + (size_t)h * SEQ * 64;
  const unsigned short* Qhp = Qh + (size_t)h * SEQ * 64;
  const unsigned short* Vtp = Vt + (size_t)h * SEQ * 64;  // tiled [128][64][32]
  // K staging source offset (shorts): row = lane>>3, chunk^row (128-B rows)
  const int kLaneOffK = (lane >> 3) * 64 + ((lane & 7) ^ (lane >> 3)) * 8;

  for (int ph = 0; ph < 2; ++ph) {
    const int qt = ph ? (127 - b) : b;
    const int qg = qt * 32 + ql;
    const int dt = qt;  // diagonal 32-tile
    bf8 qf[4];
    {
      const unsigned short* qp = Qhp + (size_t)qg * 64 + hi * 8;
      qf[0] = *reinterpret_cast<const bf8*>(qp);
      qf[1] = *reinterpret_cast<const bf8*>(qp + 16);
      qf[2] = *reinterpret_cast<const bf8*>(qp + 32);
      qf[3] = *reinterpret_cast<const bf8*>(qp + 48);
    }
    f32x16 o0 = {}, o1 = {};
    float m = -1e30f, l = 0.f;

    const int nt = (dt >= w) ? ((dt - w) >> 2) + 1 : 0;
    if (nt > 0) {
      STAGE4K(Khp, w, kbuf);
      STAGE4KV(Vtp, w, vbuf);
      for (int i = 0; i < nt; ++i) {
        const int t = w + 4 * i;
        STEP32(t, (i + 1 < nt));
      }
    }
    __syncthreads();  // all staging consumed; buffers reusable as sO

    // ---- 4-way split-K merge via LDS (sO overlays staging region) ----
#pragma unroll
    for (int r = 0; r < 16; ++r) {
      int dr = (r & 3) + 8 * (r >> 2) + 4 * hi;
      sO[w * 2048 + dr * 32 + ql] = o0[r];
      sO[w * 2048 + (32 + dr) * 32 + ql] = o1[r];
    }
    if (hi == 0) { sM[w * 32 + ql] = m; sL[w * 32 + ql] = l; }
    __syncthreads();
    {
      const int q = tid & 31;
      const int dblk = tid >> 5;  // 0..7, 8 d-values each
      float m0 = sM[q], m1 = sM[32 + q], m2 = sM[64 + q], m3 = sM[96 + q];
      float mn = fmaxf(fmaxf(m0, m1), fmaxf(m2, m3));
      float a0 = __builtin_amdgcn_exp2f(m0 - mn);
      float a1 = __builtin_amdgcn_exp2f(m1 - mn);
      float a2 = __builtin_amdgcn_exp2f(m2 - mn);
      float a3 = __builtin_amdgcn_exp2f(m3 - mn);
      float inv = 1.f / (a0 * sL[q] + a1 * sL[32 + q] + a2 * sL[64 + q] + a3 * sL[96 + q]);
      a0 *= inv; a1 *= inv; a2 *= inv; a3 *= inv;
      unsigned short* cp = ctx + (size_t)(qt * 32 + q) * DM + h * HD + dblk * 8;
#pragma unroll
      for (int j = 0; j < 8; j += 2) {
        int d = dblk * 8 + j;
        float v0 = sO[d * 32 + q] * a0 + sO[2048 + d * 32 + q] * a1 +
                   sO[4096 + d * 32 + q] * a2 + sO[6144 + d * 32 + q] * a3;
        float v1 = sO[(d + 1) * 32 + q] * a0 + sO[2048 + (d + 1) * 32 + q] * a1 +
                   sO[4096 + (d + 1) * 32 + q] * a2 + sO[6144 + (d + 1) * 32 + q] * a3;
        *reinterpret_cast<unsigned int*>(cp + j) = cvtpk(v0, v1);
      }
    }
    __syncthreads();  // merge reads done before phase-2 restage
  }
}

extern "C" void kernel_launch(void* const* d_in, const int* in_sizes, int n_in,
                              void* d_out, int out_size, void* d_ws, size_t ws_size,
                              hipStream_t stream) {
  const float* x  = (const float*)d_in[0];
  const float* Wq = (const float*)d_in[1];
  const float* Wk = (const float*)d_in[2];
  const float* Wv = (const float*)d_in[3];
  const float* Wo = (const float*)d_in[4];
  const float* bo = (const float*)d_in[5];

  unsigned short* xb = (unsigned short*)d_ws;
  unsigned short* wt = xb + (size_t)SEQ * DM;
  unsigned short* Qh = wt + (size_t)4 * DM * DM;
  unsigned short* Kh = Qh + (size_t)SEQ * DM;
  unsigned short* Vt = Kh + (size_t)SEQ * DM;
  unsigned short* cx = Vt + (size_t)SEQ * DM;

  const float qscale = 1.4426950408889634f / 8.0f;  // log2(e)/sqrt(HD)

  // fused prologue: 2304 tw-blocks + 3072 cvt-blocks
  k_pro<<<dim3(2304 + (SEQ * DM) / 1024), 256, 0, stream>>>(
      x, Wq, Wk, Wv, Wo, xb, wt);
  // fused QKV GEMM over Bt=[2304][768] (wt holds Wq^T|Wk^T|Wv^T contiguous)
  k_gemm2<3, 18><<<dim3(SEQ / 128 * 18), 256, 0, stream>>>(
      xb, wt, Qh, Kh, Vt, nullptr, nullptr, qscale);
  k_attn<<<dim3(768), 256, 0, stream>>>(Qh, Kh, Vt, cx);
  k_gemm2<2, 6><<<dim3(SEQ / 128 * 6), 256, 0, stream>>>(
      cx, wt + (size_t)3 * DM * DM, nullptr, nullptr, nullptr,
      (float*)d_out, bo, 1.0f);
}